// Round 5
// baseline (274.358 us; speedup 1.0000x reference)
//
#include <hip/hip_runtime.h>
#include <math.h>

#define FDIM 128
#define RDIM 20
#define BN   8000
#define NPAIR 512000
#define PB   64
#define ROWS 8

typedef __attribute__((ext_vector_type(8))) short short8v;
typedef __attribute__((ext_vector_type(4))) float float4v;

// fast ShiftedSoftplus: max(x,0) + log(1+exp(-|x|)) - ln2, fast intrinsics
__device__ __forceinline__ float sspf_fast(float x) {
    return fmaxf(x, 0.0f) + __logf(1.0f + __expf(-fabsf(x))) - 0.69314718055994531f;
}
// precise version for the small row-GEMMs (cheap there)
__device__ __forceinline__ float sspf(float x) {
    return fmaxf(x, 0.0f) + log1pf(expf(-fabsf(x))) - 0.69314718055994531f;
}

__device__ __forceinline__ unsigned short f2bf(float x) {
    union { float f; unsigned u; } v; v.f = x;
    unsigned r = (v.u + 0x7FFFu + ((v.u >> 16) & 1u)) >> 16;
    return (unsigned short)r;
}

// ---------------------------------------------------------------------------
// CSR preprocessing: histogram -> exclusive scan -> scatter
__global__ __launch_bounds__(256) void hist_kernel(
    const int* __restrict__ idx_i, int* __restrict__ cnt)
{
    const int p = blockIdx.x * 256 + threadIdx.x;
    if (p < NPAIR) atomicAdd(&cnt[idx_i[p]], 1);
}

__global__ __launch_bounds__(1024) void scan_kernel(
    const int* __restrict__ cnt, int* __restrict__ cursor)
{
    __shared__ int part[1024];
    const int t = threadIdx.x;
    int v[8]; int sum = 0;
    #pragma unroll
    for (int k = 0; k < 8; ++k) {
        const int i = t * 8 + k;
        const int c = (i < BN) ? cnt[i] : 0;
        v[k] = sum; sum += c;
    }
    part[t] = sum;
    __syncthreads();
    for (int off = 1; off < 1024; off <<= 1) {
        const int x = (t >= off) ? part[t - off] : 0;
        __syncthreads();
        part[t] += x;
        __syncthreads();
    }
    const int base = (t == 0) ? 0 : part[t - 1];
    #pragma unroll
    for (int k = 0; k < 8; ++k) {
        const int i = t * 8 + k;
        if (i < BN) cursor[i] = base + v[k];
    }
}

// after this kernel cursor[r] = end offset of row r's segment
__global__ __launch_bounds__(256) void scatter_kernel(
    const int* __restrict__ idx_i, int* __restrict__ cursor, int* __restrict__ perm)
{
    const int p = blockIdx.x * 256 + threadIdx.x;
    if (p < NPAIR) {
        const int pos = atomicAdd(&cursor[idx_i[p]], 1);
        perm[pos] = p;
    }
}

// ---------------------------------------------------------------------------
// C[p, :] = act(A[p, :] @ W + bias), 16 rows per block, 256 threads.
template<bool SSP, bool BF16OUT>
__global__ __launch_bounds__(256) void rowgemm_kernel(
    const float* __restrict__ A, const float* __restrict__ W,
    const float* __restrict__ bias, void* __restrict__ Cv)
{
    __shared__ float rowlds[16 * 128];
    const int tid = threadIdx.x;
    const int blk = blockIdx.x;
    for (int s = tid; s < 16 * 128; s += 256)
        rowlds[s] = A[blk * 16 * 128 + s];
    __syncthreads();

    const int lane = tid & 63;
    const int wave = tid >> 6;
    const float b0 = bias[lane];
    const float b1 = bias[64 + lane];
    float acc[4][2];
    #pragma unroll
    for (int rr = 0; rr < 4; ++rr) { acc[rr][0] = b0; acc[rr][1] = b1; }

    #pragma unroll 4
    for (int m = 0; m < 128; ++m) {
        const float w0 = W[m * 128 + lane];
        const float w1 = W[m * 128 + 64 + lane];
        #pragma unroll
        for (int rr = 0; rr < 4; ++rr) {
            const float av = rowlds[(wave * 4 + rr) * 128 + m];
            acc[rr][0] = fmaf(av, w0, acc[rr][0]);
            acc[rr][1] = fmaf(av, w1, acc[rr][1]);
        }
    }

    #pragma unroll
    for (int rr = 0; rr < 4; ++rr) {
        const int p = blk * 16 + wave * 4 + rr;
        float v0 = acc[rr][0], v1 = acc[rr][1];
        if (SSP) { v0 = sspf(v0); v1 = sspf(v1); }
        if (BF16OUT) {
            unsigned short* C = (unsigned short*)Cv;
            C[p * 128 + lane]      = f2bf(v0);
            C[p * 128 + 64 + lane] = f2bf(v1);
        } else {
            float* C = (float*)Cv;
            C[p * 128 + lane]      = v0;
            C[p * 128 + 64 + lane] = v1;
        }
    }
}

// ---------------------------------------------------------------------------
// Row-centric MFMA pairs kernel, software-pipelined, 2 barriers/chunk.
// Block b owns rows [b*8, b*8+8). h gathered in bf16 (L2-resident).
__global__ __launch_bounds__(256) void pairs_v5(
    const float* __restrict__ f_ij, const int* __restrict__ idx_i,
    const int* __restrict__ idx_j, const float* __restrict__ rcut,
    const float* __restrict__ Wf1, const float* __restrict__ bf1,
    const float* __restrict__ Wf2, const float* __restrict__ bf2,
    const unsigned short* __restrict__ h2, const int* __restrict__ rowEnd,
    const int* __restrict__ perm, float* __restrict__ agg)
{
    __shared__ unsigned short act[64 * 128];   // act^T bf16 [pair][c], swz ((p&7)<<4)
    __shared__ unsigned short xbuf[64 * 128];  // X bf16 [c][pair], swz ((c&7)<<4)
    __shared__ float         rcs[2][PB];
    __shared__ int           jjs[2][PB];
    __shared__ unsigned char rrs8[2][PB];

    const int tid = threadIdx.x;
    const int w   = tid >> 6;       // wave 0..3: owns out-cols [w*32, w*32+32)
    const int l   = tid & 63;
    const int l15 = l & 15;
    const int l4  = l >> 4;
    const int swz = (l15 & 7) << 4;

    const int row0 = blockIdx.x * ROWS;
    const int s0 = (row0 == 0) ? 0 : rowEnd[row0 - 1];
    const int s1 = rowEnd[row0 + ROWS - 1];

    // ---- weight fragments in registers ----
    short8v wf1a[2];
    #pragma unroll
    for (int kt2 = 0; kt2 < 2; ++kt2) {
        const int ck = w * 32 + kt2 * 16 + l15;
        #pragma unroll
        for (int e = 0; e < 8; ++e) {
            const int r = l4 * 8 + e;
            const float val = (r < RDIM) ? Wf1[r * 128 + ck] : 0.0f;
            wf1a[kt2][e] = (short)f2bf(val);
        }
    }
    short8v wf2a[2][4];
    #pragma unroll
    for (int mt = 0; mt < 2; ++mt) {
        const int c = w * 32 + mt * 16 + l15;
        #pragma unroll
        for (int ks = 0; ks < 4; ++ks) {
            #pragma unroll
            for (int e = 0; e < 8; ++e) {
                const int k = ks * 32 + l4 * 8 + e;
                wf2a[mt][ks][e] = (short)f2bf(Wf2[k * 128 + c]);
            }
        }
    }
    float b1v[2][4], b2v[2][4];
    #pragma unroll
    for (int t = 0; t < 2; ++t)
        #pragma unroll
        for (int j = 0; j < 4; ++j) {
            b1v[t][j] = bf1[w * 32 + t * 16 + l4 * 4 + j];
            b2v[t][j] = bf2[w * 32 + t * 16 + l4 * 4 + j];
        }

    float4v accD[2];
    accD[0] = float4v{0.f, 0.f, 0.f, 0.f};
    accD[1] = float4v{0.f, 0.f, 0.f, 0.f};

    // ---- prologue prefetch (chunk 0): perm -> f frags + meta regs ----
    short8v ffr[4];
    float4  mreg = {0.f, 0.f, 0.f, 0.f};
    {
        #pragma unroll
        for (int nt = 0; nt < 4; ++nt) {
            int q = s0 + nt * 16 + l15; if (q > NPAIR - 1) q = NPAIR - 1;
            const int pid = perm[q];
            const float* fb = f_ij + (size_t)pid * RDIM;
            float4 fa = {0.f,0.f,0.f,0.f}, fc = {0.f,0.f,0.f,0.f};
            if (l4 < 3) fa = *(const float4*)(fb + l4 * 8);
            if (l4 < 2) fc = *(const float4*)(fb + l4 * 8 + 4);
            ffr[nt][0] = (short)f2bf(fa.x); ffr[nt][1] = (short)f2bf(fa.y);
            ffr[nt][2] = (short)f2bf(fa.z); ffr[nt][3] = (short)f2bf(fa.w);
            ffr[nt][4] = (short)f2bf(fc.x); ffr[nt][5] = (short)f2bf(fc.y);
            ffr[nt][6] = (short)f2bf(fc.z); ffr[nt][7] = (short)f2bf(fc.w);
        }
        if (tid < PB) {
            int q = s0 + tid; if (q > NPAIR - 1) q = NPAIR - 1;
            const int pid = perm[q];
            mreg.x = rcut[pid];
            mreg.y = __int_as_float(idx_j[pid]);
            mreg.z = __int_as_float(idx_i[pid]);
        }
    }

    int tb = 0;
    for (int s = s0; s < s1; s += PB, tb ^= 1) {
        // ---- meta LDS write for this chunk (wave 0) ----
        if (tid < PB) {
            const int q = s + tid;
            rcs[tb][tid]  = (q < s1) ? mreg.x : 0.0f;   // pad slots contribute 0
            jjs[tb][tid]  = __float_as_int(mreg.y);
            rrs8[tb][tid] = (unsigned char)(__float_as_int(mreg.z) - row0);
        }

        // ---- layer 1: act^T = ssp(Wf1^T x f^T + b1) -> act (bf16, LDS) ----
        #pragma unroll
        for (int kt2 = 0; kt2 < 2; ++kt2) {
            #pragma unroll
            for (int nt = 0; nt < 4; ++nt) {
                float4v acc1 = {0.f, 0.f, 0.f, 0.f};
                acc1 = __builtin_amdgcn_mfma_f32_16x16x32_bf16(wf1a[kt2], ffr[nt], acc1, 0, 0, 0);
                unsigned short pk[4];
                #pragma unroll
                for (int j = 0; j < 4; ++j)
                    pk[j] = f2bf(sspf_fast(acc1[j] + b1v[kt2][j]));
                const int row = nt * 16 + l15;
                const int byte = row * 256 + ((w * 64 + kt2 * 32 + l4 * 8) ^ swz);
                *(unsigned long long*)((char*)act + byte) =
                    (unsigned long long)pk[0] | ((unsigned long long)pk[1] << 16) |
                    ((unsigned long long)pk[2] << 32) | ((unsigned long long)pk[3] << 48);
            }
        }
        __syncthreads();   // bar1: act + meta[tb] ready

        const int sn = s + PB;

        // ---- prefetch chunk t+1: perm first (dependent loads follow) ----
        int pidn[4];
        #pragma unroll
        for (int nt = 0; nt < 4; ++nt) {
            int q = sn + nt * 16 + l15; if (q > NPAIR - 1) q = NPAIR - 1;
            pidn[nt] = perm[q];
        }
        int pidm = 0;
        if (tid < PB) {
            int q = sn + tid; if (q > NPAIR - 1) q = NPAIR - 1;
            pidm = perm[q];
        }

        // ---- hv gather for this chunk (bf16, L2-resident) ----
        unsigned long long hvb[4][2];
        #pragma unroll
        for (int nt = 0; nt < 4; ++nt) {
            const int gj = jjs[tb][nt * 16 + l15] << 7;
            hvb[nt][0] = *(const unsigned long long*)&h2[gj + w * 32 + l4 * 4];
            hvb[nt][1] = *(const unsigned long long*)&h2[gj + w * 32 + 16 + l4 * 4];
        }

        // ---- layer 2: Wij^T = Wf2^T x act^T ----
        float4v a2[2][4];
        #pragma unroll
        for (int mt = 0; mt < 2; ++mt)
            #pragma unroll
            for (int nt = 0; nt < 4; ++nt)
                a2[mt][nt] = float4v{0.f, 0.f, 0.f, 0.f};

        #pragma unroll
        for (int ks = 0; ks < 4; ++ks) {
            short8v bfr[4];
            #pragma unroll
            for (int nt = 0; nt < 4; ++nt) {
                const int row = nt * 16 + l15;
                const int byte = row * 256 + ((ks * 64 + l4 * 16) ^ swz);
                bfr[nt] = *(const short8v*)((const char*)act + byte);
            }
            #pragma unroll
            for (int mt = 0; mt < 2; ++mt)
                #pragma unroll
                for (int nt = 0; nt < 4; ++nt)
                    a2[mt][nt] = __builtin_amdgcn_mfma_f32_16x16x32_bf16(
                        wf2a[mt][ks], bfr[nt], a2[mt][nt], 0, 0, 0);
        }

        // ---- prefetch t+1 payloads (perm values now available) ----
        #pragma unroll
        for (int nt = 0; nt < 4; ++nt) {
            const float* fb = f_ij + (size_t)pidn[nt] * RDIM;
            float4 fa = {0.f,0.f,0.f,0.f}, fc = {0.f,0.f,0.f,0.f};
            if (l4 < 3) fa = *(const float4*)(fb + l4 * 8);
            if (l4 < 2) fc = *(const float4*)(fb + l4 * 8 + 4);
            ffr[nt][0] = (short)f2bf(fa.x); ffr[nt][1] = (short)f2bf(fa.y);
            ffr[nt][2] = (short)f2bf(fa.z); ffr[nt][3] = (short)f2bf(fa.w);
            ffr[nt][4] = (short)f2bf(fc.x); ffr[nt][5] = (short)f2bf(fc.y);
            ffr[nt][6] = (short)f2bf(fc.z); ffr[nt][7] = (short)f2bf(fc.w);
        }
        if (tid < PB) {
            mreg.x = rcut[pidm];
            mreg.y = __int_as_float(idx_j[pidm]);
            mreg.z = __int_as_float(idx_i[pidm]);
        }

        // ---- X build: X[p][c] = h*(Wij+b2)*rcut -> bf16, stored [c][p] ----
        #pragma unroll
        for (int nt = 0; nt < 4; ++nt) {
            const int p = nt * 16 + l15;
            const float r = rcs[tb][p];
            #pragma unroll
            for (int mt = 0; mt < 2; ++mt) {
                #pragma unroll
                for (int j = 0; j < 4; ++j) {
                    const int c = w * 32 + mt * 16 + l4 * 4 + j;
                    const float hf = __uint_as_float(
                        (unsigned)((hvb[nt][mt] >> (16 * j)) & 0xFFFFULL) << 16);
                    const float xv = hf * ((a2[mt][nt][j] + b2v[mt][j]) * r);
                    const int byte = c * 128 + ((p * 2) ^ ((c & 7) << 4));
                    *(unsigned short*)((char*)xbuf + byte) = f2bf(xv);
                }
            }
        }
        __syncthreads();   // bar2: X ready

        // ---- AGG: aggT += X^T x S^T (S built in regs from rrs8) ----
        #pragma unroll
        for (int ks = 0; ks < 2; ++ks) {
            const unsigned long long rb =
                *(const unsigned long long*)&rrs8[tb][ks * 32 + l4 * 8];
            short8v sfr;
            #pragma unroll
            for (int e = 0; e < 8; ++e) {
                const unsigned rv = (unsigned)((rb >> (8 * e)) & 0xFFull);
                sfr[e] = (rv == (unsigned)l15) ? (short)0x3F80 : (short)0;
            }
            #pragma unroll
            for (int mt = 0; mt < 2; ++mt) {
                const int c = w * 32 + mt * 16 + l15;
                const int byte = c * 128 + ((ks * 64 + l4 * 16) ^ ((c & 7) << 4));
                const short8v xfr = *(const short8v*)((const char*)xbuf + byte);
                accD[mt] = __builtin_amdgcn_mfma_f32_16x16x32_bf16(xfr, sfr, accD[mt], 0, 0, 0);
            }
        }
    }

    // ---- write out: lane holds aggT[c = w*32+mt*16+l4*4+j][r = l15] ----
    if (l15 < ROWS) {
        #pragma unroll
        for (int mt = 0; mt < 2; ++mt) {
            float4 v;
            v.x = accD[mt][0]; v.y = accD[mt][1]; v.z = accD[mt][2]; v.w = accD[mt][3];
            *(float4*)&agg[(size_t)(row0 + l15) * 128 + w * 32 + mt * 16 + l4 * 4] = v;
        }
    }
}

extern "C" void kernel_launch(void* const* d_in, const int* in_sizes, int n_in,
                              void* d_out, int out_size, void* d_ws, size_t ws_size,
                              hipStream_t stream) {
    const float* x     = (const float*)d_in[0];
    const float* f_ij  = (const float*)d_in[1];
    const int*   idx_i = (const int*)  d_in[2];
    const int*   idx_j = (const int*)  d_in[3];
    const float* rcut  = (const float*)d_in[4];
    const float* W_in  = (const float*)d_in[5];
    const float* b_in  = (const float*)d_in[6];
    const float* Wf1   = (const float*)d_in[7];
    const float* bf1   = (const float*)d_in[8];
    const float* Wf2   = (const float*)d_in[9];
    const float* bf2   = (const float*)d_in[10];
    const float* Wo1   = (const float*)d_in[11];
    const float* bo1   = (const float*)d_in[12];
    const float* Wo2   = (const float*)d_in[13];
    const float* bo2   = (const float*)d_in[14];
    float* out = (float*)d_out;

    // ws layout (10.3 MB total):
    //   h2   : bf16 [8000][128]                        2,048,000 B
    //   agg  : f32  [8000][128]                        4,096,000 B
    //   t1   : f32  [8000][128] (perm/cnt overlay)     4,096,000 B
    unsigned short* h2 = (unsigned short*)d_ws;
    float* agg = (float*)((char*)d_ws + 2048000);
    float* t1  = (float*)((char*)d_ws + 2048000 + 4096000);
    int* perm   = (int*)t1;                               // 512000 ints (t1 overlay)
    int* cnt    = (int*)((char*)t1 + (size_t)NPAIR * 4);  // 8001 ints
    int* cursor = cnt + 8001;                             // 8000 ints

    // CSR sort of pairs by idx_i
    hipMemsetAsync(cnt, 0, (BN + 1) * sizeof(int), stream);
    hist_kernel<<<NPAIR / 256, 256, 0, stream>>>(idx_i, cnt);
    scan_kernel<<<1, 1024, 0, stream>>>(cnt, cursor);
    scatter_kernel<<<NPAIR / 256, 256, 0, stream>>>(idx_i, cursor, perm);

    // h2 = bf16(x @ W_in + b_in)
    rowgemm_kernel<false, true><<<BN / 16, 256, 0, stream>>>(x, W_in, b_in, h2);

    // filter net (MFMA) + gather + MFMA segmented aggregation
    pairs_v5<<<BN / ROWS, 256, 0, stream>>>(
        f_ij, idx_i, idx_j, rcut, Wf1, bf1, Wf2, bf2, h2, cursor, perm, agg);

    // out = ssp(agg @ Wo1 + bo1) @ Wo2 + bo2
    rowgemm_kernel<true,  false><<<BN / 16, 256, 0, stream>>>(agg, Wo1, bo1, t1);
    rowgemm_kernel<false, false><<<BN / 16, 256, 0, stream>>>(t1, Wo2, bo2, out);
}

// Round 6
// 237.956 us; speedup vs baseline: 1.1530x; 1.1530x over previous
//
#include <hip/hip_runtime.h>
#include <math.h>

#define FDIM 128
#define RDIM 20
#define BN   8000
#define NPAIR 512000
#define PB   64
#define ROWS 8

typedef __attribute__((ext_vector_type(8))) short short8v;
typedef __attribute__((ext_vector_type(4))) float float4v;

// fast ShiftedSoftplus: max(x,0) + log(1+exp(-|x|)) - ln2, fast intrinsics
__device__ __forceinline__ float sspf_fast(float x) {
    return fmaxf(x, 0.0f) + __logf(1.0f + __expf(-fabsf(x))) - 0.69314718055994531f;
}
// precise version for the small row-GEMMs (cheap there)
__device__ __forceinline__ float sspf(float x) {
    return fmaxf(x, 0.0f) + log1pf(expf(-fabsf(x))) - 0.69314718055994531f;
}

__device__ __forceinline__ unsigned short f2bf(float x) {
    union { float f; unsigned u; } v; v.f = x;
    unsigned r = (v.u + 0x7FFFu + ((v.u >> 16) & 1u)) >> 16;
    return (unsigned short)r;
}

// ---------------------------------------------------------------------------
// CSR preprocessing: histogram -> exclusive scan -> scatter
__global__ __launch_bounds__(256) void hist_kernel(
    const int* __restrict__ idx_i, int* __restrict__ cnt)
{
    const int p = blockIdx.x * 256 + threadIdx.x;
    if (p < NPAIR) atomicAdd(&cnt[idx_i[p]], 1);
}

__global__ __launch_bounds__(1024) void scan_kernel(
    const int* __restrict__ cnt, int* __restrict__ cursor)
{
    __shared__ int part[1024];
    const int t = threadIdx.x;
    int v[8]; int sum = 0;
    #pragma unroll
    for (int k = 0; k < 8; ++k) {
        const int i = t * 8 + k;
        const int c = (i < BN) ? cnt[i] : 0;
        v[k] = sum; sum += c;
    }
    part[t] = sum;
    __syncthreads();
    for (int off = 1; off < 1024; off <<= 1) {
        const int x = (t >= off) ? part[t - off] : 0;
        __syncthreads();
        part[t] += x;
        __syncthreads();
    }
    const int base = (t == 0) ? 0 : part[t - 1];
    #pragma unroll
    for (int k = 0; k < 8; ++k) {
        const int i = t * 8 + k;
        if (i < BN) cursor[i] = base + v[k];
    }
}

// after this kernel cursor[r] = end offset of row r's segment
__global__ __launch_bounds__(256) void scatter_kernel(
    const int* __restrict__ idx_i, int* __restrict__ cursor, int* __restrict__ perm)
{
    const int p = blockIdx.x * 256 + threadIdx.x;
    if (p < NPAIR) {
        const int pos = atomicAdd(&cursor[idx_i[p]], 1);
        perm[pos] = p;
    }
}

// ---------------------------------------------------------------------------
// C[p, :] = act(A[p, :] @ W + bias), 16 rows per block, 256 threads.
template<bool SSP, bool BF16OUT>
__global__ __launch_bounds__(256) void rowgemm_kernel(
    const float* __restrict__ A, const float* __restrict__ W,
    const float* __restrict__ bias, void* __restrict__ Cv)
{
    __shared__ float rowlds[16 * 128];
    const int tid = threadIdx.x;
    const int blk = blockIdx.x;
    for (int s = tid; s < 16 * 128; s += 256)
        rowlds[s] = A[blk * 16 * 128 + s];
    __syncthreads();

    const int lane = tid & 63;
    const int wave = tid >> 6;
    const float b0 = bias[lane];
    const float b1 = bias[64 + lane];
    float acc[4][2];
    #pragma unroll
    for (int rr = 0; rr < 4; ++rr) { acc[rr][0] = b0; acc[rr][1] = b1; }

    #pragma unroll 4
    for (int m = 0; m < 128; ++m) {
        const float w0 = W[m * 128 + lane];
        const float w1 = W[m * 128 + 64 + lane];
        #pragma unroll
        for (int rr = 0; rr < 4; ++rr) {
            const float av = rowlds[(wave * 4 + rr) * 128 + m];
            acc[rr][0] = fmaf(av, w0, acc[rr][0]);
            acc[rr][1] = fmaf(av, w1, acc[rr][1]);
        }
    }

    #pragma unroll
    for (int rr = 0; rr < 4; ++rr) {
        const int p = blk * 16 + wave * 4 + rr;
        float v0 = acc[rr][0], v1 = acc[rr][1];
        if (SSP) { v0 = sspf(v0); v1 = sspf(v1); }
        if (BF16OUT) {
            unsigned short* C = (unsigned short*)Cv;
            C[p * 128 + lane]      = f2bf(v0);
            C[p * 128 + 64 + lane] = f2bf(v1);
        } else {
            float* C = (float*)Cv;
            C[p * 128 + lane]      = v0;
            C[p * 128 + 64 + lane] = v1;
        }
    }
}

// ---------------------------------------------------------------------------
// Row-centric MFMA pairs kernel over CSR-sorted pairs (round-4 structure).
// Block b owns rows [b*ROWS, b*ROWS+ROWS). No atomics anywhere.
//   L1: act^T = ssp(Wf1^T x f^T + b1)                (f B-frags direct from global)
//   L2: Wij^T = Wf2^T x act^T + b2
//   X[p][c] = h[idx_j_p][c] * Wij[p][c] * rcut_p     (bf16, stored [c][p] in LDS)
//   AGG: aggT += X^T x S^T  (S = row-indicator, built in regs; D regs accumulate)
__global__ __launch_bounds__(256) void pairs_mfma_agg(
    const float* __restrict__ f_ij, const int* __restrict__ idx_i,
    const int* __restrict__ idx_j, const float* __restrict__ rcut,
    const float* __restrict__ Wf1, const float* __restrict__ bf1,
    const float* __restrict__ Wf2, const float* __restrict__ bf2,
    const unsigned short* __restrict__ h2, const int* __restrict__ rowEnd,
    const int* __restrict__ perm, float* __restrict__ agg)
{
    // dual-use 16 KB buffer:
    //   act phase: [pair=64][c=128] bf16, row stride 256B, XOR swz ((p&7)<<4)
    //   X   phase: [c=128][pair=64] bf16, row stride 128B, XOR swz ((c&7)<<4)
    __shared__ unsigned short xt[64 * 128];
    __shared__ int   rrs[PB];
    __shared__ int   jjs[PB];
    __shared__ float rcs[PB];

    const int tid = threadIdx.x;
    const int w   = tid >> 6;       // wave 0..3: owns cols [w*32, w*32+32)
    const int l   = tid & 63;
    const int l15 = l & 15;
    const int l4  = l >> 4;
    const int swz = (l15 & 7) << 4;

    const int row0 = blockIdx.x * ROWS;
    const int s0 = (row0 == 0) ? 0 : rowEnd[row0 - 1];
    const int s1 = rowEnd[row0 + ROWS - 1];

    // ---- weight fragments in registers ----
    short8v wf1a[2];
    #pragma unroll
    for (int kt2 = 0; kt2 < 2; ++kt2) {
        const int ck = w * 32 + kt2 * 16 + l15;
        #pragma unroll
        for (int e = 0; e < 8; ++e) {
            const int r = l4 * 8 + e;
            const float val = (r < RDIM) ? Wf1[r * 128 + ck] : 0.0f;
            wf1a[kt2][e] = (short)f2bf(val);
        }
    }
    short8v wf2a[2][4];
    #pragma unroll
    for (int mt = 0; mt < 2; ++mt) {
        const int c = w * 32 + mt * 16 + l15;
        #pragma unroll
        for (int ks = 0; ks < 4; ++ks) {
            #pragma unroll
            for (int e = 0; e < 8; ++e) {
                const int k = ks * 32 + l4 * 8 + e;
                wf2a[mt][ks][e] = (short)f2bf(Wf2[k * 128 + c]);
            }
        }
    }
    float b1v[2][4], b2v[2][4];
    #pragma unroll
    for (int t = 0; t < 2; ++t)
        #pragma unroll
        for (int j = 0; j < 4; ++j) {
            b1v[t][j] = bf1[w * 32 + t * 16 + l4 * 4 + j];
            b2v[t][j] = bf2[w * 32 + t * 16 + l4 * 4 + j];
        }

    // agg accumulator in MFMA D regs: accD[mt] holds aggT[c = w*32+mt*16+l4*4+j][r = l15]
    float4v accD[2];
    accD[0] = float4v{0.f, 0.f, 0.f, 0.f};
    accD[1] = float4v{0.f, 0.f, 0.f, 0.f};

    for (int s = s0; s < s1; s += PB) {
        __syncthreads();   // prev chunk's AGG reads of xt done; meta arrays free

        // ---- stage pair metadata (LDS) ----
        if (tid < PB) {
            const int q  = s + tid;
            const int qc = q < s1 ? q : s1 - 1;
            const int pid = perm[qc];
            rrs[tid] = idx_i[pid] - row0;            // in [0,ROWS)
            jjs[tid] = idx_j[pid];
            rcs[tid] = (q < s1) ? rcut[pid] : 0.0f;  // pad slots contribute 0
        }

        // ---- layer-1 B-frags straight from global (k-contiguous per lane) ----
        short8v ffr[4];
        #pragma unroll
        for (int nt = 0; nt < 4; ++nt) {
            const int q = s + nt * 16 + l15;
            const int pid = perm[q < s1 ? q : s1 - 1];
            const float* fb = &f_ij[(size_t)pid * RDIM];
            float4 fa = {0.f, 0.f, 0.f, 0.f}, fc = {0.f, 0.f, 0.f, 0.f};
            if (l4 < 3) fa = *(const float4*)(fb + l4 * 8);       // l4=2 -> k 16..19
            if (l4 < 2) fc = *(const float4*)(fb + l4 * 8 + 4);
            ffr[nt][0] = (short)f2bf(fa.x); ffr[nt][1] = (short)f2bf(fa.y);
            ffr[nt][2] = (short)f2bf(fa.z); ffr[nt][3] = (short)f2bf(fa.w);
            ffr[nt][4] = (short)f2bf(fc.x); ffr[nt][5] = (short)f2bf(fc.y);
            ffr[nt][6] = (short)f2bf(fc.z); ffr[nt][7] = (short)f2bf(fc.w);
        }
        __syncthreads();   // metadata ready

        // ---- prefetch h rows (bf16; consumed after L2, latency hides under MFMA) ----
        unsigned long long hvb[4][2];
        #pragma unroll
        for (int nt = 0; nt < 4; ++nt) {
            const int gj = jjs[nt * 16 + l15] << 7;
            hvb[nt][0] = *(const unsigned long long*)&h2[gj + w * 32 + l4 * 4];
            hvb[nt][1] = *(const unsigned long long*)&h2[gj + w * 32 + 16 + l4 * 4];
        }

        // ---- layer 1: act^T = ssp(Wf1^T x f^T + b1) -> xt as [pair][c] ----
        #pragma unroll
        for (int kt2 = 0; kt2 < 2; ++kt2) {
            #pragma unroll
            for (int nt = 0; nt < 4; ++nt) {
                float4v acc1 = {0.f, 0.f, 0.f, 0.f};
                acc1 = __builtin_amdgcn_mfma_f32_16x16x32_bf16(wf1a[kt2], ffr[nt], acc1, 0, 0, 0);
                unsigned short pk[4];
                #pragma unroll
                for (int j = 0; j < 4; ++j)
                    pk[j] = f2bf(sspf_fast(acc1[j] + b1v[kt2][j]));
                const int row = nt * 16 + l15;
                const int byte = row * 256 + ((w * 64 + kt2 * 32 + l4 * 8) ^ swz);
                *(unsigned long long*)((char*)xt + byte) =
                    (unsigned long long)pk[0] | ((unsigned long long)pk[1] << 16) |
                    ((unsigned long long)pk[2] << 32) | ((unsigned long long)pk[3] << 48);
            }
        }
        __syncthreads();   // act ready

        // ---- layer 2: Wij^T = Wf2^T x act^T ----
        float4v a2[2][4];
        #pragma unroll
        for (int mt = 0; mt < 2; ++mt)
            #pragma unroll
            for (int nt = 0; nt < 4; ++nt)
                a2[mt][nt] = float4v{0.f, 0.f, 0.f, 0.f};

        #pragma unroll
        for (int ks = 0; ks < 4; ++ks) {
            short8v bfr[4];
            #pragma unroll
            for (int nt = 0; nt < 4; ++nt) {
                const int row = nt * 16 + l15;
                const int byte = row * 256 + ((ks * 64 + l4 * 16) ^ swz);
                bfr[nt] = *(const short8v*)((const char*)xt + byte);
            }
            #pragma unroll
            for (int mt = 0; mt < 2; ++mt)
                #pragma unroll
                for (int nt = 0; nt < 4; ++nt)
                    a2[mt][nt] = __builtin_amdgcn_mfma_f32_16x16x32_bf16(
                        wf2a[mt][ks], bfr[nt], a2[mt][nt], 0, 0, 0);
        }
        __syncthreads();   // act fully consumed; xt free for X

        // ---- X build: X[p][c] = h*(Wij+b2)*rcut -> bf16, stored [c][p] ----
        #pragma unroll
        for (int nt = 0; nt < 4; ++nt) {
            const int p = nt * 16 + l15;
            const float r = rcs[p];
            #pragma unroll
            for (int mt = 0; mt < 2; ++mt) {
                #pragma unroll
                for (int j = 0; j < 4; ++j) {
                    const int c = w * 32 + mt * 16 + l4 * 4 + j;
                    const float hf = __uint_as_float(
                        (unsigned)((hvb[nt][mt] >> (16 * j)) & 0xFFFFULL) << 16);
                    const float xv = hf * ((a2[mt][nt][j] + b2v[mt][j]) * r);
                    const int byte = c * 128 + ((p * 2) ^ ((c & 7) << 4));
                    *(unsigned short*)((char*)xt + byte) = f2bf(xv);
                }
            }
        }
        __syncthreads();   // X ready

        // ---- AGG: aggT += X^T x S^T (S built in regs from rrs) ----
        #pragma unroll
        for (int ks = 0; ks < 2; ++ks) {
            short8v sfr;
            #pragma unroll
            for (int e = 0; e < 8; ++e) {
                const int pr = ks * 32 + l4 * 8 + e;
                sfr[e] = (rrs[pr] == l15) ? (short)0x3F80 : (short)0;  // bf16(1.0)
            }
            #pragma unroll
            for (int mt = 0; mt < 2; ++mt) {
                const int c = w * 32 + mt * 16 + l15;
                const int byte = c * 128 + ((ks * 64 + l4 * 16) ^ swz);
                const short8v xfr = *(const short8v*)((const char*)xt + byte);
                accD[mt] = __builtin_amdgcn_mfma_f32_16x16x32_bf16(xfr, sfr, accD[mt], 0, 0, 0);
            }
        }
    }

    // ---- write out: lane holds aggT[c = w*32+mt*16+l4*4+j][r = l15] ----
    if (l15 < ROWS) {
        #pragma unroll
        for (int mt = 0; mt < 2; ++mt) {
            float4 v;
            v.x = accD[mt][0]; v.y = accD[mt][1]; v.z = accD[mt][2]; v.w = accD[mt][3];
            *(float4*)&agg[(size_t)(row0 + l15) * 128 + w * 32 + mt * 16 + l4 * 4] = v;
        }
    }
}

extern "C" void kernel_launch(void* const* d_in, const int* in_sizes, int n_in,
                              void* d_out, int out_size, void* d_ws, size_t ws_size,
                              hipStream_t stream) {
    const float* x     = (const float*)d_in[0];
    const float* f_ij  = (const float*)d_in[1];
    const int*   idx_i = (const int*)  d_in[2];
    const int*   idx_j = (const int*)  d_in[3];
    const float* rcut  = (const float*)d_in[4];
    const float* W_in  = (const float*)d_in[5];
    const float* b_in  = (const float*)d_in[6];
    const float* Wf1   = (const float*)d_in[7];
    const float* bf1   = (const float*)d_in[8];
    const float* Wf2   = (const float*)d_in[9];
    const float* bf2   = (const float*)d_in[10];
    const float* Wo1   = (const float*)d_in[11];
    const float* bo1   = (const float*)d_in[12];
    const float* Wo2   = (const float*)d_in[13];
    const float* bo2   = (const float*)d_in[14];
    float* out = (float*)d_out;

    // ws layout:
    //   h2   : bf16 [8000][128]                        2,048,000 B
    //   agg  : f32  [8000][128]                        4,096,000 B
    //   t1   : f32  [8000][128] (perm/cnt overlay)     4,096,000 B
    unsigned short* h2 = (unsigned short*)d_ws;
    float* agg = (float*)((char*)d_ws + 2048000);
    float* t1  = (float*)((char*)d_ws + 2048000 + 4096000);
    int* perm   = (int*)t1;                               // 512000 ints (t1 overlay)
    int* cnt    = (int*)((char*)t1 + (size_t)NPAIR * 4);  // 8001 ints
    int* cursor = cnt + 8001;                             // 8000 ints

    // CSR sort of pairs by idx_i
    hipMemsetAsync(cnt, 0, (BN + 1) * sizeof(int), stream);
    hist_kernel<<<NPAIR / 256, 256, 0, stream>>>(idx_i, cnt);
    scan_kernel<<<1, 1024, 0, stream>>>(cnt, cursor);
    scatter_kernel<<<NPAIR / 256, 256, 0, stream>>>(idx_i, cursor, perm);

    // h2 = bf16(x @ W_in + b_in)
    rowgemm_kernel<false, true><<<BN / 16, 256, 0, stream>>>(x, W_in, b_in, h2);

    // filter net (MFMA) + gather + MFMA segmented aggregation
    pairs_mfma_agg<<<BN / ROWS, 256, 0, stream>>>(
        f_ij, idx_i, idx_j, rcut, Wf1, bf1, Wf2, bf2, h2, cursor, perm, agg);

    // out = ssp(agg @ Wo1 + bo1) @ Wo2 + bo2
    rowgemm_kernel<true,  false><<<BN / 16, 256, 0, stream>>>(agg, Wo1, bo1, t1);
    rowgemm_kernel<false, false><<<BN / 16, 256, 0, stream>>>(t1, Wo2, bo2, out);
}